// Round 12
// baseline (293.378 us; speedup 1.0000x reference)
//
#include <hip/hip_runtime.h>
#include <hip/hip_bf16.h>

#define D 112
#define HEADS 28
#define HDIM 4
#define SEQ 512
#define BATCH 16
#define NTOK (BATCH*SEQ)
#define NBASES 8
#define NKNOT 12
#define KTOT (D*9)          // 1008 real K; padded to 1024 for MFMA
#define KPAD 1024
#define NKT (KPAD/32)       // 32 K-steps
#define TM 16               // tokens per block in kan GEMM

typedef __attribute__((ext_vector_type(8))) __bf16 bf16x8;
typedef __attribute__((ext_vector_type(4))) float f32x4;

__device__ __forceinline__ float dot4(float4 a, float4 b) {
    return a.x*b.x + a.y*b.y + a.z*b.z + a.w*b.w;
}

__device__ __forceinline__ unsigned short f2bf(float f) {
    unsigned u = __float_as_uint(f);
    unsigned r = u + 0x7FFFu + ((u >> 16) & 1u);   // RNE
    return (unsigned short)(r >> 16);
}

// ---------------- QKV projection (8 tokens/block) ----------------
// q is scaled by 0.5*log2(e) so attention scores are in log2 units.
__global__ __launch_bounds__(256) void qkv_kernel(
    const float* __restrict__ hin,
    const float* __restrict__ qw, const float* __restrict__ qb,
    const float* __restrict__ kw, const float* __restrict__ kb,
    const float* __restrict__ vw, const float* __restrict__ vb,
    int l, float* __restrict__ q, float* __restrict__ k, float* __restrict__ v)
{
    __shared__ float4 xs[8][28];
    int tid = threadIdx.x;
    int t0 = blockIdx.x * 8;
    const float4* src = (const float4*)(hin + (size_t)t0 * D);
    for (int e = tid; e < 8*28; e += 256) xs[e/28][e%28] = src[e];
    __syncthreads();
    for (int o = tid; o < 3*D; o += 256) {
        int m = o / D, j = o % D;
        const float* wbase = (m==0) ? qw : (m==1) ? kw : vw;
        const float* bbase = (m==0) ? qb : (m==1) ? kb : vb;
        const float4* wrow = (const float4*)(wbase + (size_t)(l*D + j) * D);
        float acc[8];
        #pragma unroll
        for (int t=0;t<8;++t) acc[t]=0.f;
        for (int c = 0; c < 28; ++c) {
            float4 wc = wrow[c];
            #pragma unroll
            for (int t = 0; t < 8; ++t) acc[t] += dot4(wc, xs[t][c]);
        }
        float bias = bbase[l*D + j];
        float scl = (m==0) ? 0.5f * 1.44269504088896f : 1.0f;  // q/sqrt(4) * log2(e)
        float* dst = (m==0) ? q : (m==1) ? k : v;
        int h = j >> 2, hd = j & 3;
        #pragma unroll
        for (int t = 0; t < 8; ++t) {
            int n = t0 + t; int b = n >> 9; int s = n & 511;
            dst[((size_t)(b*HEADS + h) * SEQ + s) * HDIM + hd] = (acc[t] + bias) * scl;
        }
    }
}

// ---------------- attention: fixed-bias softmax, 2 queries/thread ----------------
// LDS-issue is the bottleneck pipe: 3 LDS reads per key per wave now serve
// 128 queries (2/thread), halving per-CU LDS instruction demand.
__global__ __launch_bounds__(128) void attn_kernel(
    const float* __restrict__ q, const float* __restrict__ k, const float* __restrict__ v,
    const int* __restrict__ mask, float* __restrict__ ctx)
{
    __shared__ float4 sk[SEQ], sv[SEQ];
    __shared__ float smf[SEQ];
    int tid = threadIdx.x;
    int bh = blockIdx.x >> 1, qt = blockIdx.x & 1;
    int b = bh / HEADS, h = bh % HEADS;
    const float4* kk = (const float4*)k + (size_t)bh*SEQ;
    const float4* vv = (const float4*)v + (size_t)bh*SEQ;
    for (int i = tid; i < SEQ; i += 128) {
        sk[i] = kk[i]; sv[i] = vv[i];
        smf[i] = mask[b*SEQ + i] ? -23.0831169f : -1e9f;   // -16*log2(e) | masked
    }
    __syncthreads();
    int s0 = qt*256 + tid;           // query 0
    int s1 = s0 + 128;               // query 1
    const float4* qp = (const float4*)q + (size_t)bh*SEQ;
    float4 qv0 = qp[s0], qv1 = qp[s1];
    float sum0 = 0.f, sum1 = 0.f;
    float a00=0.f, a01=0.f, a02=0.f, a03=0.f;
    float a10=0.f, a11=0.f, a12=0.f, a13=0.f;
    #pragma unroll 8
    for (int kp = 0; kp < SEQ; ++kp) {
        float4 k4 = sk[kp];
        float mf = smf[kp];
        float4 v4 = sv[kp];
        float sc0 = fmaf(qv0.x, k4.x, fmaf(qv0.y, k4.y,
                    fmaf(qv0.z, k4.z, fmaf(qv0.w, k4.w, mf))));
        float sc1 = fmaf(qv1.x, k4.x, fmaf(qv1.y, k4.y,
                    fmaf(qv1.z, k4.z, fmaf(qv1.w, k4.w, mf))));
        float p0 = __builtin_exp2f(sc0);
        float p1 = __builtin_exp2f(sc1);
        sum0 += p0; sum1 += p1;
        a00 = fmaf(p0, v4.x, a00); a01 = fmaf(p0, v4.y, a01);
        a02 = fmaf(p0, v4.z, a02); a03 = fmaf(p0, v4.w, a03);
        a10 = fmaf(p1, v4.x, a10); a11 = fmaf(p1, v4.y, a11);
        a12 = fmaf(p1, v4.z, a12); a13 = fmaf(p1, v4.w, a13);
    }
    float inv0 = 1.f / sum0, inv1 = 1.f / sum1;
    float4 o0 = {a00*inv0, a01*inv0, a02*inv0, a03*inv0};
    float4 o1 = {a10*inv1, a11*inv1, a12*inv1, a13*inv1};
    ((float4*)ctx)[(size_t)(b*SEQ + s0)*HEADS + h] = o0;   // ctx in (B,S,D) layout
    ((float4*)ctx)[(size_t)(b*SEQ + s1)*HEADS + h] = o1;
}

// ---------------- O-projection + residual + LN1 (4 tokens/block) ----------------
__global__ __launch_bounds__(256) void oproj_ln_kernel(
    const float* __restrict__ ctx, const float* __restrict__ hin,
    const float* __restrict__ ow, const float* __restrict__ ob,
    const float* __restrict__ g, const float* __restrict__ bta,
    int l, float* __restrict__ hout)
{
    __shared__ float4 sc[4][28];
    __shared__ float so[4][112];
    int tid = threadIdx.x;
    int t0 = blockIdx.x * 4;
    const float4* src = (const float4*)(ctx + (size_t)t0*D);
    if (tid < 112) sc[tid/28][tid%28] = src[tid];
    __syncthreads();
    if (tid < 224) {
        int j = tid % D, tg = tid / D;
        const float4* wrow = (const float4*)(ow + (size_t)(l*D + j)*D);
        float a0=0.f, a1=0.f;
        for (int c = 0; c < 28; ++c) {
            float4 wc = wrow[c];
            a0 += dot4(wc, sc[2*tg][c]);
            a1 += dot4(wc, sc[2*tg+1][c]);
        }
        float bias = ob[l*D + j];
        so[2*tg][j]   = a0 + bias + hin[(size_t)(t0+2*tg)*D + j];
        so[2*tg+1][j] = a1 + bias + hin[(size_t)(t0+2*tg+1)*D + j];
    }
    __syncthreads();
    int w = tid >> 6, lane = tid & 63;
    float x0 = so[w][lane];
    float x1 = (lane + 64 < D) ? so[w][lane+64] : 0.f;
    float s1 = x0 + x1, s2 = x0*x0 + x1*x1;
    #pragma unroll
    for (int off = 32; off; off >>= 1) { s1 += __shfl_xor(s1, off, 64); s2 += __shfl_xor(s2, off, 64); }
    float mu = s1 * (1.f/112.f);
    float var = s2 * (1.f/112.f) - mu*mu;
    float rs = rsqrtf(var + 1e-5f);
    for (int i = lane; i < D; i += 64)
        hout[(size_t)(t0+w)*D + i] = (so[w][i] - mu) * rs * g[l*D+i] + bta[l*D+i];
}

// ---------------- Wb prep: fold (spline_w*scaler, base_w) into bf16 B-fragment layout ----
__global__ void wb_prep_kernel(
    const float* __restrict__ base_w, const float* __restrict__ spline_w,
    const float* __restrict__ scaler, unsigned short* __restrict__ wb)
{
    int idx = blockIdx.x * 256 + threadIdx.x;
    if (idx >= 2 * NKT * D * 32) return;
    int kk = idx & 31;
    int j  = (idx >> 5) % D;
    int kt = ((idx >> 5) / D) % NKT;
    int l  = idx / (32 * D * NKT);
    int k = kt * 32 + kk;
    float val = 0.f;
    if (k < KTOT) {
        int i = k / 9, b = k % 9;
        size_t ji = ((size_t)l * D + j) * D + i;
        val = (b == 8) ? base_w[ji] : spline_w[ji * NBASES + b] * scaler[ji];
    }
    wb[idx] = f2bf(val);
}

// ---------------- KAN via bf16 MFMA + residual + LN2 (16 tokens/block, 4 waves) ---------
__global__ __launch_bounds__(256) void kan_ln_v3_kernel(
    const float* __restrict__ hin, const float* __restrict__ grid,
    const unsigned short* __restrict__ wb,
    const float* __restrict__ g, const float* __restrict__ bta,
    int l, int gstride, float* __restrict__ hout)
{
    __shared__ __align__(16) unsigned short act_lds[TM][1032];  // row pad -> 2-way bank (free)
    __shared__ float so[TM][D];
    int tid = threadIdx.x;
    int t0 = blockIdx.x * TM;

    // ---- basis phase: 1792 (token,i) pairs, 7 per thread ----
    for (int e = tid; e < TM * D; e += 256) {
        int t = e / D, i = e % D;
        float xv = hin[(size_t)(t0 + t) * D + i];
        float si = xv / (1.f + __expf(-xv));
        const float* grp = grid + i * gstride;
        float gr[NKNOT];
        #pragma unroll
        for (int ii = 0; ii < NKNOT; ++ii) gr[ii] = grp[ii];
        float bs[11];
        #pragma unroll
        for (int ii = 0; ii < 11; ++ii) bs[ii] = (xv >= gr[ii] && xv < gr[ii+1]) ? 1.f : 0.f;
        #pragma unroll
        for (int kk = 1; kk <= 3; ++kk) {
            #pragma unroll
            for (int ii = 0; ii + kk <= 10; ++ii) {
                float left  = (xv - gr[ii]) / (gr[ii+kk] - gr[ii]) * bs[ii];
                float right = (gr[ii+kk+1] - xv) / (gr[ii+kk+1] - gr[ii+1]) * bs[ii+1];
                bs[ii] = left + right;
            }
        }
        unsigned short* arow = &act_lds[t][i * 9];
        #pragma unroll
        for (int b = 0; b < 8; ++b) arow[b] = f2bf(bs[b]);
        arow[8] = f2bf(si);
    }
    // zero-pad k = 1008..1031
    for (int e = tid; e < TM * 24; e += 256)
        act_lds[e / 24][KTOT + e % 24] = 0;
    __syncthreads();

    // ---- MFMA GEMM phase: wave w owns j-tiles 2w, 2w+1 (7 tiles total) ----
    int w = tid >> 6, lane = tid & 63;
    int m = lane & 15, g4 = lane >> 4;
    int jt0 = 2 * w, jt1 = 2 * w + 1;
    f32x4 acc0 = {0.f,0.f,0.f,0.f}, acc1 = {0.f,0.f,0.f,0.f};
    const bf16x8* wbl = (const bf16x8*)wb + (size_t)l * NKT * D * 4;
    #pragma unroll 4
    for (int kt = 0; kt < NKT; ++kt) {
        bf16x8 a = *(const bf16x8*)&act_lds[m][kt * 32 + g4 * 8];
        bf16x8 b0 = wbl[((size_t)kt * D + jt0 * 16 + m) * 4 + g4];
        acc0 = __builtin_amdgcn_mfma_f32_16x16x32_bf16(a, b0, acc0, 0, 0, 0);
        if (jt1 < 7) {
            bf16x8 b1 = wbl[((size_t)kt * D + jt1 * 16 + m) * 4 + g4];
            acc1 = __builtin_amdgcn_mfma_f32_16x16x32_bf16(a, b1, acc1, 0, 0, 0);
        }
    }

    // ---- epilogue: D + residual -> so ----
    #pragma unroll
    for (int r = 0; r < 4; ++r) {
        int t = g4 * 4 + r;
        int j0 = jt0 * 16 + m;
        so[t][j0] = acc0[r] + hin[(size_t)(t0 + t) * D + j0];
        if (jt1 < 7) {
            int j1 = jt1 * 16 + m;
            so[t][j1] = acc1[r] + hin[(size_t)(t0 + t) * D + j1];
        }
    }
    __syncthreads();

    // ---- LN phase: 4 waves x 4 tokens ----
    for (int tt = 0; tt < 4; ++tt) {
        int t = w * 4 + tt;
        float x0 = so[t][lane];
        float x1 = (lane + 64 < D) ? so[t][lane + 64] : 0.f;
        float s1 = x0 + x1, s2 = x0*x0 + x1*x1;
        #pragma unroll
        for (int off = 32; off; off >>= 1) { s1 += __shfl_xor(s1, off, 64); s2 += __shfl_xor(s2, off, 64); }
        float mu = s1 * (1.f/112.f);
        float var = s2 * (1.f/112.f) - mu*mu;
        float rs = rsqrtf(var + 1e-5f);
        for (int ii = lane; ii < D; ii += 64)
            hout[(size_t)(t0 + t) * D + ii] = (so[t][ii] - mu) * rs * g[l*D + ii] + bta[l*D + ii];
    }
}

// ---------------- classifier: f32 output ----------------
__global__ __launch_bounds__(64) void cls_kernel(
    const float* __restrict__ h, const float* __restrict__ cw, const float* __restrict__ cb,
    float* __restrict__ out)
{
    int tid = threadIdx.x;
    if (tid < BATCH*2) {
        int b = tid >> 1, c = tid & 1;
        const float* hr = h + (size_t)b*SEQ*D;   // token s=0
        const float* wr = cw + c*D;
        float a = 0.f;
        for (int i = 0; i < D; ++i) a += hr[i]*wr[i];
        out[b*2 + c] = a + cb[c];
    }
}

// ---------------- ws-too-small sentinel (diagnostic) ----------------
__global__ void sentinel_kernel(float* __restrict__ out, int nel)
{
    int i = threadIdx.x;
    if (i < nel) out[i] = 1e30f;
}

extern "C" void kernel_launch(void* const* d_in, const int* in_sizes, int n_in,
                              void* d_out, int out_size, void* d_ws, size_t ws_size,
                              hipStream_t stream)
{
    const float* x      = (const float*)d_in[0];
    const int*   mask   = (const int*)  d_in[1];
    const float* grid   = (const float*)d_in[2];
    const float* qw     = (const float*)d_in[3];
    const float* qb     = (const float*)d_in[4];
    const float* kw     = (const float*)d_in[5];
    const float* kb     = (const float*)d_in[6];
    const float* vw     = (const float*)d_in[7];
    const float* vb     = (const float*)d_in[8];
    const float* ow     = (const float*)d_in[9];
    const float* ob     = (const float*)d_in[10];
    const float* ln1g   = (const float*)d_in[11];
    const float* ln1b   = (const float*)d_in[12];
    const float* ln2g   = (const float*)d_in[13];
    const float* ln2b   = (const float*)d_in[14];
    const float* base_w = (const float*)d_in[15];
    const float* spline_w = (const float*)d_in[16];
    const float* scaler = (const float*)d_in[17];
    const float* cls_w  = (const float*)d_in[18];
    const float* cls_b  = (const float*)d_in[19];

    size_t SZ = (size_t)NTOK * D;              // 917504 floats per buffer
    size_t WBN = (size_t)2 * NKT * D * 32;     // 229376 bf16 elements
    size_t need = 6 * SZ * sizeof(float) + WBN * sizeof(unsigned short);  // ~22.5 MB
    if (ws_size < need) {
        sentinel_kernel<<<1, 64, 0, stream>>>((float*)d_out, out_size);
        return;
    }
    float* ws = (float*)d_ws;
    float* q   = ws;
    float* k   = q + SZ;
    float* v   = k + SZ;
    float* ctx = v + SZ;
    float* hA  = ctx + SZ;
    float* hB  = hA + SZ;
    unsigned short* wbuf = (unsigned short*)(hB + SZ);

    int gstride = (in_sizes[2] == NKNOT) ? 0 : NKNOT;

    wb_prep_kernel<<<(int)((WBN + 255)/256), 256, 0, stream>>>(
        base_w, spline_w, scaler, wbuf);

    const float* hin = x;
    for (int l = 0; l < 2; ++l) {
        qkv_kernel<<<NTOK/8, 256, 0, stream>>>(hin, qw,qb,kw,kb,vw,vb, l, q,k,v);
        attn_kernel<<<BATCH*HEADS*2, 128, 0, stream>>>(q,k,v,mask,ctx);
        oproj_ln_kernel<<<NTOK/4, 256, 0, stream>>>(ctx, hin, ow, ob, ln1g, ln1b, l, hA);
        kan_ln_v3_kernel<<<NTOK/TM, 256, 0, stream>>>(hA, grid, wbuf, ln2g, ln2b, l, gstride, hB);
        hin = hB;
    }
    cls_kernel<<<1, 64, 0, stream>>>(hB, cls_w, cls_b, (float*)d_out);
}